// Round 8
// baseline (220.785 us; speedup 1.0000x reference)
//
#include <hip/hip_runtime.h>
#include <hip/hip_bf16.h>
#include <math.h>

#define Bv 8
#define Tv 32
#define Nv 500
#define NP 512           /* padded node dim for the AGG GEMM */
#define Fin 64
#define Hv 128
#define Ev 8000
#define Kv 3
#define BT (Bv*Tv)       /* 256 */
#define ROWS (BT*Nv)     /* 128000 */
#define NCOL (BT*Fin)    /* 16384: X2b/AGG2 row length */
#define TP (Tv+2)        /* 34 LDS time rows (1 pad each side) */
#define KK (Kv*Hv)       /* 384 */
#define LDSROW 144       /* 288B row stride */

typedef __attribute__((ext_vector_type(8))) short s8v;   // 8 bf16
typedef __attribute__((ext_vector_type(4))) float f4v;   // MFMA acc

// branch-free erf (A&S 7.1.26, |err| <= 1.5e-7)
__device__ __forceinline__ float gelu_exact(float v){
    float t  = v*0.70710678118654752440f;
    float ax = fabsf(t);
    float k  = __builtin_amdgcn_rcpf(fmaf(0.3275911f, ax, 1.0f));
    float p  = k*fmaf(k, fmaf(k, fmaf(k, fmaf(k, 1.061405429f, -1.453152027f),
                                      1.421413741f), -0.284496736f), 0.254829592f);
    float e  = __expf(-ax*ax);
    float er = fmaf(-p, e, 1.0f);
    er = copysignf(er, t);
    return 0.5f*v*(1.0f + er);
}
__device__ __forceinline__ short f2bs(float f){
    union { __hip_bfloat16 h; short s; } u;
    u.h = __float2bfloat16(f);
    return u.s;
}
__device__ __forceinline__ float b2f(short s){
    union { unsigned int i; float f; } u;
    u.i = ((unsigned int)(unsigned short)s) << 16;
    return u.f;
}

// ---- prep0: [0] degree+dinv | [1,64] zero A_f32 | [65,2064] x -> X2b + XT
//      | [2065,2112] XT n-pad zero | [2113,2176] weight repacks ----
__global__ __launch_bounds__(1024) void k_prep0(const float* __restrict__ x,
        short* __restrict__ X2b, short* __restrict__ XT,
        float* __restrict__ Af32,
        const float* __restrict__ W, const float* __restrict__ Wg,
        const float* __restrict__ Wr,
        short* __restrict__ W2, short* __restrict__ Wgt, short* __restrict__ Wrt,
        const int* __restrict__ ei, const float* __restrict__ ew,
        float* __restrict__ dinv){
    __shared__ float sdeg[Nv];
    int bid = blockIdx.x;
    int tid = threadIdx.x;
    if (bid == 0){
        if (tid < Nv) sdeg[tid] = 1.0f;             // self-loop weight pre-added
        __syncthreads();
        for (int e = tid; e < Ev; e += 1024)
            atomicAdd(&sdeg[ei[Ev + e]], ew[e]);
        __syncthreads();
        if (tid < Nv){
            float d = sdeg[tid];
            dinv[tid] = (d > 0.f) ? rsqrtf(d) : 0.f;
        }
    } else if (bid <= 64){
        int i = (bid-1)*1024 + tid;                 // 65536 float4 = 512x512 f32
        ((float4*)Af32)[i] = make_float4(0.f,0.f,0.f,0.f);
    } else if (bid <= 2064){
        int gid = (bid-65)*1024 + tid;              // ROWS*16 float4 elements
        int row = gid >> 4, c4 = gid & 15;
        int bt = row / Nv;
        int n  = row - bt*Nv;
        float4 v = ((const float4*)x)[gid];
        short4 sv;
        sv.x = f2bs(v.x); sv.y = f2bs(v.y); sv.z = f2bs(v.z); sv.w = f2bs(v.w);
        *(short4*)(X2b + (size_t)n*NCOL + bt*64 + c4*4) = sv;
        int colb = bt*64 + c4*4;                    // XT[col][n] (col-major-ish)
        XT[(size_t)(colb+0)*NP + n] = sv.x;
        XT[(size_t)(colb+1)*NP + n] = sv.y;
        XT[(size_t)(colb+2)*NP + n] = sv.z;
        XT[(size_t)(colb+3)*NP + n] = sv.w;
    } else if (bid <= 2112){
        int idx = (bid-2065)*1024 + tid;            // 16384 cols * 3 short4 pads
        int col = idx/3, rem = idx - col*3;
        short4 z = {0,0,0,0};
        *(short4*)(XT + (size_t)col*NP + Nv + rem*4) = z;
    } else {
        int idx = (bid-2113)*1024 + tid;
        if (idx < Hv*Hv*Kv){
            int o = idx/(Hv*Kv);
            int rem = idx - o*(Hv*Kv);
            int i = rem/Kv, k = rem - i*Kv;
            W2[o*KK + k*Hv + i] = f2bs(W[idx]);
        } else if (idx < Hv*Hv*Kv + Hv*64){
            int j = idx - Hv*Hv*Kv;
            int o = j >> 6, k = j & 63;
            Wgt[j] = f2bs(Wg[k*Hv + o]);
        } else if (idx < Hv*Hv*Kv + 2*Hv*64){
            int j = idx - Hv*Hv*Kv - Hv*64;
            int o = j >> 6, k = j & 63;
            Wrt[j] = f2bs(Wr[k*Hv + o]);
        }
    }
}

// ---- prep1: atomic scatter of normalized edge weights into dense A_f32.
//      atomicAdd accumulates duplicate (s,d) edges exactly like segment_sum. ----
__global__ __launch_bounds__(1024) void k_prep1(const int* __restrict__ ei,
        const float* __restrict__ ew, const float* __restrict__ dinv,
        float* __restrict__ Af32){
    int e = blockIdx.x*1024 + threadIdx.x;
    if (e < Ev){
        int s = ei[e], d = ei[Ev + e];
        atomicAdd(&Af32[(size_t)d*NP + s], dinv[s]*ew[e]*dinv[d]);
    }
    if (blockIdx.x == 0 && threadIdx.x < Nv){      // self-loop diag: dv*1*dv
        float dv = dinv[threadIdx.x];
        atomicAdd(&Af32[(size_t)threadIdx.x*NP + threadIdx.x], dv*dv);
    }
}

// ---- cvt: A_f32 -> A_bf16 ----
__global__ __launch_bounds__(1024) void k_cvt(const float* __restrict__ Af32,
        short* __restrict__ Ab){
    int i = blockIdx.x*1024 + threadIdx.x;          // 65536 float4
    float4 v = ((const float4*)Af32)[i];
    short4 s;
    s.x = f2bs(v.x); s.y = f2bs(v.y); s.z = f2bs(v.z); s.w = f2bs(v.w);
    ((short4*)Ab)[i] = s;
}

// ---- gemm: AGG2[n][col] = sum_k Ab[n][k] * XT[col][k]  (M=512,N=16384,K=512)
// grid 512 = 4 i-tiles x 128 j-tiles; 4 waves; wave owns 32 j-cols, 128 i-rows.
// Dense-GEMM replacement for the latency-bound SpMM gather: deep independent
// MFMA work (256 MFMA/wave), A is 512KB L2-resident, XT j-stripe per XCD
// (bid%8 fixed across the 4 i-tiles sharing a jt since 128%8==0) -> L2 reuse.
__global__ __launch_bounds__(256) void k_gemm(const short* __restrict__ Ab,
        const short* __restrict__ XT, short* __restrict__ AGG2){
    int tid  = threadIdx.x;
    int w    = tid >> 6;
    int lane = tid & 63;
    int quad = lane >> 4;
    int laneo = lane & 15;
    int bid = blockIdx.x;
    int jt = bid & 127, it = bid >> 7;
    int i0 = it*128;
    int j0 = jt*128 + w*32;

    f4v acc[8][2];
    #pragma unroll
    for (int m = 0; m < 8; ++m){
        acc[m][0] = (f4v){0.f,0.f,0.f,0.f};
        acc[m][1] = (f4v){0.f,0.f,0.f,0.f};
    }
    #pragma unroll 2
    for (int ks = 0; ks < 16; ++ks){
        int k0 = ks*32 + quad*8;
        s8v bfr[2];
        #pragma unroll
        for (int nt = 0; nt < 2; ++nt)
            bfr[nt] = *(const s8v*)(XT + (size_t)(j0 + nt*16 + laneo)*NP + k0);
        #pragma unroll
        for (int m = 0; m < 8; ++m){
            s8v afr = *(const s8v*)(Ab + (size_t)(i0 + m*16 + laneo)*NP + k0);
            acc[m][0] = __builtin_amdgcn_mfma_f32_16x16x32_bf16(afr, bfr[0], acc[m][0], 0,0,0);
            acc[m][1] = __builtin_amdgcn_mfma_f32_16x16x32_bf16(afr, bfr[1], acc[m][1], 0,0,0);
        }
    }
    #pragma unroll
    for (int m = 0; m < 8; ++m){
        #pragma unroll
        for (int r = 0; r < 4; ++r){
            int row = i0 + m*16 + quad*4 + r;
            if (row < Nv){
                #pragma unroll
                for (int nt = 0; nt < 2; ++nt)
                    AGG2[(size_t)row*NCOL + j0 + nt*16 + laneo] = f2bs(acc[m][nt][r]);
            }
        }
    }
}

// ---- mega kernel: EXACT round-1 structure (best measured: 67us) + fast erf.
//      GCN GEMM (K=64) -> GELU -> LDS; conv GEMM (K=384); residual GEMM;
//      bias+GELU+residual+LayerNorm -> out. 4 waves, 4 nodes/block. ----
__global__ __launch_bounds__(256, 2) void k_mega(
        const short* __restrict__ AGG2, const short* __restrict__ X2b,
        const short* __restrict__ W2, const short* __restrict__ Wgt,
        const short* __restrict__ Wrt,
        const float* __restrict__ bg, const float* __restrict__ btm,
        const float* __restrict__ br, const float* __restrict__ lw,
        const float* __restrict__ lb, float* __restrict__ out){
    __shared__ short hs[4*TP*LDSROW];      // 39168 B
    __shared__ float red[Tv][4][2];
    int tid  = threadIdx.x;
    int w    = tid >> 6;
    int lane = tid & 63;
    int quad = lane >> 4;
    int laneo = lane & 15;
    int bid = blockIdx.x;
    int b  = bid / 125;
    int n0 = (bid - b*125) * 4;
    int o_base = w*32;

    float bgv[2], bbv[2], brv[2], lwv[2], lbv[2];
    #pragma unroll
    for (int nt = 0; nt < 2; ++nt){
        int o = o_base + nt*16 + laneo;
        bgv[nt] = bg[o]; bbv[nt] = btm[o]; brv[nt] = br[o];
        lwv[nt] = lw[o]; lbv[nt] = lb[o];
    }

    s8v bwg[2][2];
    #pragma unroll
    for (int nt = 0; nt < 2; ++nt){
        const short* wp = Wgt + (o_base + nt*16 + laneo)*64 + quad*8;
        bwg[nt][0] = *(const s8v*)wp;
        bwg[nt][1] = *(const s8v*)(wp + 32);
    }

    if (tid < 128){
        int node = tid >> 5, rem = tid & 31;
        int tp = (rem >> 4)*(TP-1), c8 = rem & 15;
        s8v z = {0,0,0,0,0,0,0,0};
        *(s8v*)&hs[node*(TP*LDSROW) + tp*LDSROW + c8*8] = z;
    }

    for (int g = 0; g < 4; ++g){
        int n = n0 + g;
        const short* ap = AGG2 + ((size_t)n*BT + b*Tv)*64;
        #pragma unroll
        for (int m = 0; m < 2; ++m){
            const short* arp = ap + (m*16 + laneo)*64 + quad*8;
            s8v a0 = *(const s8v*)arp;
            s8v a1 = *(const s8v*)(arp + 32);
            f4v h0 = {0.f,0.f,0.f,0.f}, h1 = {0.f,0.f,0.f,0.f};
            h0 = __builtin_amdgcn_mfma_f32_16x16x32_bf16(a0, bwg[0][0], h0, 0,0,0);
            h0 = __builtin_amdgcn_mfma_f32_16x16x32_bf16(a1, bwg[0][1], h0, 0,0,0);
            h1 = __builtin_amdgcn_mfma_f32_16x16x32_bf16(a0, bwg[1][0], h1, 0,0,0);
            h1 = __builtin_amdgcn_mfma_f32_16x16x32_bf16(a1, bwg[1][1], h1, 0,0,0);
            #pragma unroll
            for (int r = 0; r < 4; ++r){
                int tp = m*16 + quad*4 + r + 1;
                short* hrow = &hs[g*(TP*LDSROW) + tp*LDSROW];
                hrow[o_base + laneo]      = f2bs(gelu_exact(h0[r] + bgv[0]));
                hrow[o_base + 16 + laneo] = f2bs(gelu_exact(h1[r] + bgv[1]));
            }
        }
    }

    s8v breg[2][12], bwr[2][2];
    #pragma unroll
    for (int nt = 0; nt < 2; ++nt){
        int o = o_base + nt*16 + laneo;
        const short* wp = W2 + o*KK + quad*8;
        #pragma unroll
        for (int s = 0; s < 12; ++s)
            breg[nt][s] = *(const s8v*)(wp + s*32);
        const short* wr = Wrt + o*64 + quad*8;
        bwr[nt][0] = *(const s8v*)wr;
        bwr[nt][1] = *(const s8v*)(wr + 32);
    }
    __syncthreads();

    for (int g = 0; g < 4; ++g){
        int n = n0 + g;
        f4v acc[2][2];
        #pragma unroll
        for (int m = 0; m < 2; ++m)
            #pragma unroll
            for (int nt = 0; nt < 2; ++nt)
                acc[m][nt] = (f4v){0.f,0.f,0.f,0.f};
        #pragma unroll
        for (int m = 0; m < 2; ++m){
            #pragma unroll
            for (int s = 0; s < 12; ++s){
                int k  = s >> 2;
                int i0 = (s & 3) * 32;
                int tp = m*16 + laneo + k;
                s8v a = *(const s8v*)&hs[g*(TP*LDSROW) + tp*LDSROW + i0 + quad*8];
                acc[m][0] = __builtin_amdgcn_mfma_f32_16x16x32_bf16(a, breg[0][s], acc[m][0], 0,0,0);
                acc[m][1] = __builtin_amdgcn_mfma_f32_16x16x32_bf16(a, breg[1][s], acc[m][1], 0,0,0);
            }
        }
        f4v racc[2][2];
        #pragma unroll
        for (int m = 0; m < 2; ++m)
            #pragma unroll
            for (int nt = 0; nt < 2; ++nt)
                racc[m][nt] = (f4v){0.f,0.f,0.f,0.f};
        const short* xp = X2b + ((size_t)n*BT + b*Tv)*64;
        #pragma unroll
        for (int m = 0; m < 2; ++m){
            const short* xrp = xp + (m*16 + laneo)*64 + quad*8;
            s8v a0 = *(const s8v*)xrp;
            s8v a1 = *(const s8v*)(xrp + 32);
            racc[m][0] = __builtin_amdgcn_mfma_f32_16x16x32_bf16(a0, bwr[0][0], racc[m][0], 0,0,0);
            racc[m][0] = __builtin_amdgcn_mfma_f32_16x16x32_bf16(a1, bwr[0][1], racc[m][0], 0,0,0);
            racc[m][1] = __builtin_amdgcn_mfma_f32_16x16x32_bf16(a0, bwr[1][0], racc[m][1], 0,0,0);
            racc[m][1] = __builtin_amdgcn_mfma_f32_16x16x32_bf16(a1, bwr[1][1], racc[m][1], 0,0,0);
        }
        size_t obase = ((size_t)b*Tv*Nv + n)*Hv;
        float yv[2][2][4];
        float srow[2][4], ssrow[2][4];
        #pragma unroll
        for (int m = 0; m < 2; ++m)
            #pragma unroll
            for (int r = 0; r < 4; ++r){ srow[m][r] = 0.f; ssrow[m][r] = 0.f; }
        #pragma unroll
        for (int m = 0; m < 2; ++m){
            #pragma unroll
            for (int nt = 0; nt < 2; ++nt){
                #pragma unroll
                for (int r = 0; r < 4; ++r){
                    float gv = gelu_exact(acc[m][nt][r] + bbv[nt]);
                    float y = gv + racc[m][nt][r] + brv[nt];
                    yv[m][nt][r] = y;
                    srow[m][r] += y; ssrow[m][r] += y*y;
                }
            }
        }
        #pragma unroll
        for (int m = 0; m < 2; ++m)
            #pragma unroll
            for (int r = 0; r < 4; ++r){
                #pragma unroll
                for (int msk = 8; msk >= 1; msk >>= 1){
                    srow[m][r]  += __shfl_xor(srow[m][r],  msk, 64);
                    ssrow[m][r] += __shfl_xor(ssrow[m][r], msk, 64);
                }
            }
        if (laneo == 0){
            #pragma unroll
            for (int m = 0; m < 2; ++m)
                #pragma unroll
                for (int r = 0; r < 4; ++r){
                    int t = m*16 + quad*4 + r;
                    red[t][w][0] = srow[m][r];
                    red[t][w][1] = ssrow[m][r];
                }
        }
        __syncthreads();
        #pragma unroll
        for (int m = 0; m < 2; ++m){
            #pragma unroll
            for (int r = 0; r < 4; ++r){
                int t = m*16 + quad*4 + r;
                float s  = red[t][0][0] + red[t][1][0] + red[t][2][0] + red[t][3][0];
                float ss = red[t][0][1] + red[t][1][1] + red[t][2][1] + red[t][3][1];
                float mu = s * (1.f/128.f);
                float var = fmaxf(ss * (1.f/128.f) - mu*mu, 0.f);
                float rstd = rsqrtf(var + 1e-5f);
                #pragma unroll
                for (int nt = 0; nt < 2; ++nt){
                    int o = o_base + nt*16 + laneo;
                    out[obase + (size_t)t*Nv*Hv + o] =
                        (yv[m][nt][r] - mu)*rstd*lwv[nt] + lbv[nt];
                }
            }
        }
        __syncthreads();
    }
}

extern "C" void kernel_launch(void* const* d_in, const int* in_sizes, int n_in,
                              void* d_out, int out_size, void* d_ws, size_t ws_size,
                              hipStream_t stream){
    const float* x   = (const float*)d_in[0];
    const int*   ei  = (const int*)d_in[1];
    const float* ew  = (const float*)d_in[2];
    const float* Wg  = (const float*)d_in[3];
    const float* bg  = (const float*)d_in[4];
    const float* Wtm = (const float*)d_in[5];
    const float* btm = (const float*)d_in[6];
    const float* lw  = (const float*)d_in[7];
    const float* lb  = (const float*)d_in[8];
    const float* Wr  = (const float*)d_in[9];
    const float* br  = (const float*)d_in[10];
    float* out = (float*)d_out;

    char* ws = (char*)d_ws;
    float* dinv = (float*)(ws + 0);            // 2048 B
    float* Af32 = (float*)(ws + 4096);         // 1 MB (512x512 f32)
    short* Ab   = (short*)(ws + 1052672);      // 512 KB (512x512 bf16)
    short* W2   = (short*)(ws + 1576960);      // 98304 B
    short* Wgt  = (short*)(ws + 1675264);      // 16384 B
    short* Wrt  = (short*)(ws + 1691648);      // 16384 B
    short* X2b  = (short*)(ws + 1708032);      // 16.384 MB  (n, bt*64+c)
    short* XT   = (short*)(ws + 18092032);     // 16.777 MB  (bt*64+c, n-pad512)
    short* AGG2 = (short*)(ws + 34869248);     // 16.384 MB  (n, bt*64+c)

    k_prep0<<<2177, 1024, 0, stream>>>(x, X2b, XT, Af32, Wtm, Wg, Wr,
                                       W2, Wgt, Wrt, ei, ew, dinv);
    k_prep1<<<8, 1024, 0, stream>>>(ei, ew, dinv, Af32);
    k_cvt  <<<64, 1024, 0, stream>>>(Af32, Ab);
    k_gemm <<<512, 256, 0, stream>>>(Ab, XT, AGG2);
    k_mega <<<(Bv*Nv)/4, 256, 0, stream>>>(AGG2, X2b, W2, Wgt, Wrt,
                                           bg, btm, br, lw, lb, out);
}